// Round 1
// 195.402 us; speedup vs baseline: 1.0743x; 1.0743x over previous
//
#include <hip/hip_runtime.h>
#include <stdint.h>
#include <math.h>

#define NPTS 16384
#define DEV 62
#define NEVENT 2048
#define NSAMPLE 64
#define CH 64
#define NBATCH 4
#define STOT (NBATCH * NEVENT)               // 8192 queries
#define M_PER_BATCH (NEVENT * NSAMPLE * CH)  // 8,388,608 elements per batch

// Output layout (f32): [0 .. 16383] = new_xy (4,2048,2);
// [16384 ..) = new_events (4,2048,64,64), 4096 floats per query region.
// Each query's own output region doubles as inter-kernel scratch (d_ws unused):
//   slots [0..63]   neighbor indices (int bits)      written by knn
//   slots [64..127] per-channel means                written by stats
//   slot  [128]     inv_std (replicated)             written by reduce_std
//   slot  [129]     partial sum of centered^2        written by stats
// finalize reads its own region's scratch into LDS, syncs, overwrites region.
#define OUT1_BASE 16384
#define REG_STRIDE (NSAMPLE * CH)   // 4096
#define SL_MEAN 64
#define SL_INV 128
#define SL_SS 129

// ---------------------------------------------------------------------------
// XCD-aware remap (perf-only heuristic, results identical for any mapping):
// blocks dispatch round-robin across the 8 XCDs (blockIdx % 8 == XCD).
// Map so XCD x only processes batch (x & 3): per-XCD gather working set drops
// from 16 MB (all batches' events) to 4.1 MB -> L2-resident (4 MiB/XCD).
// Bijection: x = blk & 7 selects batch b = x&3 and half h = x>>2;
// j = blk >> 3 walks queries within the half.
// ---------------------------------------------------------------------------
__device__ __forceinline__ int swz_query8192(int blk) {
    int x = blk & 7;
    int j = blk >> 3;              // 0..1023
    return (x & 3) * NEVENT + (x >> 2) * (NEVENT / 2) + j;
}
__device__ __forceinline__ int swz_group2048(int blk) {
    int x = blk & 7;
    int j = blk >> 3;              // 0..255
    return (x & 3) * (NEVENT / 4) + (x >> 2) * (NEVENT / 8) + j;
}

// ---------------------------------------------------------------------------
// Pass 1: ball query on RAW f32 coords (bf16-input theory falsified in R5).
// One wave per query; scans xy in 256-point super-chunks (4x64 loads issued
// up-front for ILP -> 4x fewer dependent-latency steps than the 64-pt loop);
// ballot-compacts in-radius indices ascending (== jnp.sort ascending +
// take-first-64); early exit at super-chunk granularity. Overscanned
// sub-chunks cannot store (pos < NSAMPLE guard) -> results identical.
// Distance replicates XLA:CPU f32 arithmetic (FMA in the k=2 contraction
// only) -- DO NOT TOUCH the FP ops or their order (established R3-R5).
// ---------------------------------------------------------------------------
__global__ __launch_bounds__(256) void knn_kernel(
    const float2* __restrict__ xy,            // f32 (B,N,2), raw
    const int* __restrict__ fps,              // (B,NEVENT)
    float* __restrict__ out)
{
    int grp  = swz_group2048(blockIdx.x);
    int wave = grp * 4 + (threadIdx.x >> 6);
    int lane = threadIdx.x & 63;
    int b = wave >> 11;                       // / NEVENT

    const float2* xyb = xy + b * NPTS;
    int qi = fps[wave];
    float2 q = xyb[qi];
    if (lane == 0) ((float2*)out)[wave] = q;  // exact f32 passthrough (passed R3+)

    float ssq = __fadd_rn(__fmul_rn(q.x, q.x), __fmul_rn(q.y, q.y));
    const float thr = 0.01f;                  // f32 constant in the traced graph

    int* regidx = (int*)(out + OUT1_BASE + (size_t)wave * REG_STRIDE);
    int m = 0;
    int first = -1;

    for (int base = 0; base < NPTS; base += 256) {
        // issue all 4 chunk loads before consuming any (ILP over L2 latency)
        float2 p0 = xyb[base       + lane];
        float2 p1 = xyb[base +  64 + lane];
        float2 p2 = xyb[base + 128 + lane];
        float2 p3 = xyb[base + 192 + lane];

        auto proc = [&](float2 p, int idxbase) {
            float ssp = __fadd_rn(__fmul_rn(p.x, p.x), __fmul_rn(p.y, p.y));
            float dot = __builtin_fmaf(q.y, p.y, __fmul_rn(q.x, p.x));   // k=2 FMA chain
            float d   = __fsub_rn(__fadd_rn(ssq, ssp), __fmul_rn(2.0f, dot));
            bool ok = !(d > thr);             // ref excludes when sqrdist > r^2
            unsigned long long bal = __ballot(ok);
            if (first < 0 && bal != 0ull)
                first = idxbase + (__ffsll((unsigned long long)bal) - 1);
            if (ok) {
                int pos = m + __popcll(bal & ((1ull << lane) - 1ull));
                if (pos < NSAMPLE) regidx[pos] = idxbase + lane;
            }
            m += __popcll(bal);
        };
        proc(p0, base);
        proc(p1, base + 64);
        proc(p2, base + 128);
        proc(p3, base + 192);
        if (m >= NSAMPLE) break;              // wave-uniform (m from ballot)
    }
    // fewer than 64 in radius: fill with first in-radius index. m >= 1: the
    // self-point distance is ~ +/-4e-7 regardless of FMA placement, << 0.01.
    if (m < NSAMPLE) {
        for (int p = m + lane; p < NSAMPLE; p += 64)
            regidx[p] = first;
    }
}

// ---------------------------------------------------------------------------
// Pass 2: gather raw f32 values + per-(s,channel) mean over 64 samples ->
// region scratch; per-block sum of centered^2 -> region scratch.
// Thread layout: c2 = channel pair (0..31), kq = sample group (0..7).
// Lanes 0..30 read contiguous float2 slices of a 248 B events row; lane 31
// reads the xy pair (channels 62,63).
// ---------------------------------------------------------------------------
__global__ __launch_bounds__(256) void stats_kernel(
    const float2* __restrict__ xy,
    const float* __restrict__ ev,             // f32 (B,N,62), raw
    float* __restrict__ out)
{
    int s = swz_query8192(blockIdx.x);
    int b = s >> 11;
    int tid = threadIdx.x;
    float* reg = out + OUT1_BASE + (size_t)s * REG_STRIDE;

    __shared__ int sidx[NSAMPLE];
    __shared__ float ssum[2][256];
    __shared__ float smean[CH];
    __shared__ float swred[4];

    if (tid < NSAMPLE) sidx[tid] = ((const int*)reg)[tid];
    __syncthreads();

    int c2 = tid & 31;
    int kq = tid >> 5;

    const float* evb = ev + (size_t)b * NPTS * DEV;
    const float2* xyb = xy + b * NPTS;

    float g0[8], g1[8];
    float a0 = 0.f, a1 = 0.f;
#pragma unroll
    for (int j = 0; j < 8; ++j) {
        int row = sidx[8 * j + kq];
        float2 v;
        if (c2 < 31) v = *(const float2*)(evb + (size_t)row * DEV + 2 * c2);
        else         v = xyb[row];
        g0[j] = v.x; g1[j] = v.y;
        a0 += v.x;   a1 += v.y;
    }
    ssum[0][tid] = a0;
    ssum[1][tid] = a1;
    __syncthreads();

    if (tid < CH) {
        int which = tid >> 5, cc = tid & 31;
        float t = 0.f;
#pragma unroll
        for (int q = 0; q < 8; ++q) t += ssum[which][q * 32 + cc];
        smean[2 * cc + which] = t * (1.0f / NSAMPLE);
    }
    __syncthreads();

    if (tid < CH) reg[SL_MEAN + tid] = smean[tid];

    float m0 = smean[2 * c2], m1 = smean[2 * c2 + 1];
    float ss = 0.f;
#pragma unroll
    for (int j = 0; j < 8; ++j) {
        float c0 = g0[j] - m0;
        float c1 = g1[j] - m1;
        ss += c0 * c0 + c1 * c1;
    }

    for (int off = 32; off > 0; off >>= 1) ss += __shfl_down(ss, off, 64);
    if ((tid & 63) == 0) swred[tid >> 6] = ss;
    __syncthreads();
    if (tid == 0) reg[SL_SS] = swred[0] + swred[1] + swred[2] + swred[3];
}

// ---------------------------------------------------------------------------
// Pass 3: per-batch std (ddof=1), f64 accumulation; replicate inv_std into
// slot SL_INV of every region of this batch.
// ---------------------------------------------------------------------------
__global__ __launch_bounds__(256) void reduce_std_kernel(float* __restrict__ out)
{
    int b = blockIdx.x;
    int tid = threadIdx.x;
    double acc = 0.0;
    for (int i = tid; i < NEVENT; i += 256)
        acc += (double)out[OUT1_BASE + (size_t)(b * NEVENT + i) * REG_STRIDE + SL_SS];
    __shared__ double sd[256];
    __shared__ float sinv;
    sd[tid] = acc;
    __syncthreads();
    for (int off = 128; off > 0; off >>= 1) {
        if (tid < off) sd[tid] += sd[tid + off];
        __syncthreads();
    }
    if (tid == 0) {
        double stdv = sqrt(sd[0] / (double)(M_PER_BATCH - 1));
        sinv = (float)(1.0 / (stdv + 1e-5));
    }
    __syncthreads();
    float inv = sinv;
    for (int i = tid; i < NEVENT; i += 256)
        out[OUT1_BASE + (size_t)(b * NEVENT + i) * REG_STRIDE + SL_INV] = inv;
}

// ---------------------------------------------------------------------------
// Pass 4: finalize. Read own region's scratch into LDS, sync, re-gather raw
// f32 values (events now per-XCD L2-resident via swizzle), normalize +
// affine, overwrite the region. float2 slot for (k=8j+kq, pair c2) =
// 256*j + tid: coalesced.
// ---------------------------------------------------------------------------
__global__ __launch_bounds__(256) void finalize_kernel(
    const float2* __restrict__ xy,
    const float* __restrict__ ev,
    const float* __restrict__ alpha,          // f32 [64]
    const float* __restrict__ beta,           // f32 [64]
    float* __restrict__ out)
{
    int s = swz_query8192(blockIdx.x);
    int b = s >> 11;
    int tid = threadIdx.x;
    float* reg = out + OUT1_BASE + (size_t)s * REG_STRIDE;

    __shared__ int sidx[NSAMPLE];
    __shared__ float sm[CH], sa[CH], sbet[CH];
    __shared__ float sinv;

    if (tid < NSAMPLE) {
        sidx[tid] = ((const int*)reg)[tid];
        sm[tid] = reg[SL_MEAN + tid];
    } else if (tid < 128) {
        sa[tid - 64] = alpha[tid - 64];
        sbet[tid - 64] = beta[tid - 64];
    } else if (tid == 128) {
        sinv = reg[SL_INV];
    }
    __syncthreads();

    int c2 = tid & 31;
    int kq = tid >> 5;
    float inv = sinv;

    const float* evb = ev + (size_t)b * NPTS * DEV;
    const float2* xyb = xy + b * NPTS;

    float m0 = sm[2 * c2],   m1 = sm[2 * c2 + 1];
    float al0 = sa[2 * c2],  al1 = sa[2 * c2 + 1];
    float be0 = sbet[2 * c2], be1 = sbet[2 * c2 + 1];

    float2* outp = (float2*)reg;
#pragma unroll
    for (int j = 0; j < 8; ++j) {
        int row = sidx[8 * j + kq];
        float2 v;
        if (c2 < 31) v = *(const float2*)(evb + (size_t)row * DEV + 2 * c2);
        else         v = xyb[row];
        float2 r;
        r.x = al0 * ((v.x - m0) * inv) + be0;
        r.y = al1 * ((v.y - m1) * inv) + be1;
        outp[256 * j + tid] = r;
    }
}

extern "C" void kernel_launch(void* const* d_in, const int* in_sizes, int n_in,
                              void* d_out, int out_size, void* d_ws, size_t ws_size,
                              hipStream_t stream) {
    const float2* xy    = (const float2*)d_in[0];
    const float*  ev    = (const float*)d_in[1];
    const int*    fps   = (const int*)d_in[2];
    const float*  alpha = (const float*)d_in[3];
    const float*  beta  = (const float*)d_in[4];
    float* out = (float*)d_out;
    (void)d_ws; (void)ws_size;   // intentionally unused

    knn_kernel<<<STOT / 4, 256, 0, stream>>>(xy, fps, out);
    stats_kernel<<<STOT, 256, 0, stream>>>(xy, ev, out);
    reduce_std_kernel<<<NBATCH, 256, 0, stream>>>(out);
    finalize_kernel<<<STOT, 256, 0, stream>>>(xy, ev, alpha, beta, out);
}

// Round 2
// 193.640 us; speedup vs baseline: 1.0841x; 1.0091x over previous
//
#include <hip/hip_runtime.h>
#include <stdint.h>
#include <math.h>

#define NPTS 16384
#define DEV 62
#define NEVENT 2048
#define NSAMPLE 64
#define CH 64
#define NBATCH 4
#define STOT (NBATCH * NEVENT)               // 8192 queries
#define M_PER_BATCH (NEVENT * NSAMPLE * CH)  // 8,388,608 elements per batch

// Output layout (f32): [0 .. 16383] = new_xy (4,2048,2);
// [16384 ..) = new_events (4,2048,64,64), 4096 floats per query region.
// Each query's own output region doubles as inter-kernel scratch (d_ws unused):
//   slots [0..63]   neighbor indices (int bits)      written by knn_stats
//   slots [64..127] per-channel means                written by knn_stats
//   slot  [128]     inv_std (replicated)             written by reduce_std
//   slot  [129]     partial sum of centered^2        written by knn_stats
// finalize reads its own region's scratch into LDS, syncs, overwrites region.
#define OUT1_BASE 16384
#define REG_STRIDE (NSAMPLE * CH)   // 4096
#define SL_MEAN 64
#define SL_INV 128
#define SL_SS 129

// ---------------------------------------------------------------------------
// XCD-aware remap (perf-only heuristic, results identical for any mapping):
// blocks dispatch round-robin across the 8 XCDs (blockIdx % 8 == XCD).
// Map so XCD x only processes batch (x & 3): per-XCD gather working set drops
// from 16 MB (all batches' events) to 4.1 MB -> L2-resident (4 MiB/XCD).
// ---------------------------------------------------------------------------
__device__ __forceinline__ int swz_query8192(int blk) {
    int x = blk & 7;
    int j = blk >> 3;              // 0..1023
    return (x & 3) * NEVENT + (x >> 2) * (NEVENT / 2) + j;
}
__device__ __forceinline__ int swz_group2048(int blk) {
    int x = blk & 7;
    int j = blk >> 3;              // 0..255
    return (x & 3) * (NEVENT / 4) + (x >> 2) * (NEVENT / 8) + j;
}

// ---------------------------------------------------------------------------
// Pass 1 (FUSED knn + stats):
// Phase A: ball query on RAW f32 coords, one wave per query (4 per block).
//   Scans xy in 256-point super-chunks (4x64 loads issued up-front for ILP);
//   ballot-compacts in-radius indices ascending (== jnp.sort ascending +
//   take-first-64); early exit at super-chunk granularity. Indices go to
//   BOTH LDS (for phase B, skipping the global round-trip) and the region
//   scratch (for finalize).
//   Distance replicates XLA:CPU f32 arithmetic (FMA only in the k=2
//   contraction) -- DO NOT TOUCH the FP ops or their order (R3-R5).
// Phase B: per-query stats with the full 256-thread block, sequentially for
//   the block's 4 queries. Identical thread layout and reduction trees as
//   the previous separate stats kernel (bitwise-identical results):
//   c2 = channel pair (0..31), kq = sample group (0..7); lanes 0..30 read
//   contiguous float2 slices of a 248 B events row; lane 31 reads xy.
// ---------------------------------------------------------------------------
__global__ __launch_bounds__(256) void knn_stats_kernel(
    const float2* __restrict__ xy,            // f32 (B,N,2), raw
    const float* __restrict__ ev,             // f32 (B,N,62), raw
    const int* __restrict__ fps,              // (B,NEVENT)
    float* __restrict__ out)
{
    int grp  = swz_group2048(blockIdx.x);     // 0..2047, batch-uniform per block
    int w    = threadIdx.x >> 6;              // wave id 0..3
    int lane = threadIdx.x & 63;
    int wave = grp * 4 + w;                   // query id 0..8191
    int b    = grp >> 9;                      // batch (uniform across block)

    __shared__ int   sidx[4][NSAMPLE];
    __shared__ float ssum[2][256];
    __shared__ float smean[CH];
    __shared__ float swred[4];

    // ---- phase A: knn ----
    const float2* xyb = xy + b * NPTS;
    int qi = fps[wave];
    float2 q = xyb[qi];
    if (lane == 0) ((float2*)out)[wave] = q;  // exact f32 passthrough (passed R3+)

    float ssq = __fadd_rn(__fmul_rn(q.x, q.x), __fmul_rn(q.y, q.y));
    const float thr = 0.01f;                  // f32 constant in the traced graph

    int* regidx = (int*)(out + OUT1_BASE + (size_t)wave * REG_STRIDE);
    int m = 0;
    int first = -1;

    for (int base = 0; base < NPTS; base += 256) {
        // issue all 4 chunk loads before consuming any (ILP over L2 latency)
        float2 p0 = xyb[base       + lane];
        float2 p1 = xyb[base +  64 + lane];
        float2 p2 = xyb[base + 128 + lane];
        float2 p3 = xyb[base + 192 + lane];

        auto proc = [&](float2 p, int idxbase) {
            float ssp = __fadd_rn(__fmul_rn(p.x, p.x), __fmul_rn(p.y, p.y));
            float dot = __builtin_fmaf(q.y, p.y, __fmul_rn(q.x, p.x));   // k=2 FMA chain
            float d   = __fsub_rn(__fadd_rn(ssq, ssp), __fmul_rn(2.0f, dot));
            bool ok = !(d > thr);             // ref excludes when sqrdist > r^2
            unsigned long long bal = __ballot(ok);
            if (first < 0 && bal != 0ull)
                first = idxbase + (__ffsll((unsigned long long)bal) - 1);
            if (ok) {
                int pos = m + __popcll(bal & ((1ull << lane) - 1ull));
                if (pos < NSAMPLE) {
                    regidx[pos]  = idxbase + lane;   // for finalize
                    sidx[w][pos] = idxbase + lane;   // for phase B
                }
            }
            m += __popcll(bal);
        };
        proc(p0, base);
        proc(p1, base + 64);
        proc(p2, base + 128);
        proc(p3, base + 192);
        if (m >= NSAMPLE) break;              // wave-uniform (m from ballot)
    }
    // fewer than 64 in radius: fill with first in-radius index. m >= 1: the
    // self-point distance is ~ +/-4e-7 regardless of FMA placement, << 0.01.
    if (m < NSAMPLE) {
        for (int p = m + lane; p < NSAMPLE; p += 64) {
            regidx[p]  = first;
            sidx[w][p] = first;
        }
    }

    __syncthreads();                          // all 4 waves' sidx ready

    // ---- phase B: stats, 256 threads per query, 4 queries sequentially ----
    int tid = threadIdx.x;
    int c2 = tid & 31;
    int kq = tid >> 5;
    const float* evb = ev + (size_t)b * NPTS * DEV;

    for (int qq = 0; qq < 4; ++qq) {
        int s = grp * 4 + qq;
        float* reg = out + OUT1_BASE + (size_t)s * REG_STRIDE;

        float g0[8], g1[8];
        float a0 = 0.f, a1 = 0.f;
#pragma unroll
        for (int j = 0; j < 8; ++j) {
            int row = sidx[qq][8 * j + kq];
            float2 v;
            if (c2 < 31) v = *(const float2*)(evb + (size_t)row * DEV + 2 * c2);
            else         v = xyb[row];
            g0[j] = v.x; g1[j] = v.y;
            a0 += v.x;   a1 += v.y;
        }
        ssum[0][tid] = a0;
        ssum[1][tid] = a1;
        __syncthreads();

        if (tid < CH) {
            int which = tid >> 5, cc = tid & 31;
            float t = 0.f;
#pragma unroll
            for (int p = 0; p < 8; ++p) t += ssum[which][p * 32 + cc];
            smean[2 * cc + which] = t * (1.0f / NSAMPLE);
        }
        __syncthreads();

        if (tid < CH) reg[SL_MEAN + tid] = smean[tid];

        float m0 = smean[2 * c2], m1 = smean[2 * c2 + 1];
        float ss = 0.f;
#pragma unroll
        for (int j = 0; j < 8; ++j) {
            float c0 = g0[j] - m0;
            float c1 = g1[j] - m1;
            ss += c0 * c0 + c1 * c1;
        }

        for (int off = 32; off > 0; off >>= 1) ss += __shfl_down(ss, off, 64);
        if ((tid & 63) == 0) swred[tid >> 6] = ss;
        __syncthreads();
        if (tid == 0) reg[SL_SS] = swred[0] + swred[1] + swred[2] + swred[3];
        __syncthreads();                      // protect ssum/smean/swred reuse
    }
}

// ---------------------------------------------------------------------------
// Pass 2: per-batch std (ddof=1), f64 accumulation (same tree as before);
// replicate inv_std into slot SL_INV of every region of this batch.
// ---------------------------------------------------------------------------
__global__ __launch_bounds__(256) void reduce_std_kernel(float* __restrict__ out)
{
    int b = blockIdx.x;
    int tid = threadIdx.x;
    double acc = 0.0;
    for (int i = tid; i < NEVENT; i += 256)
        acc += (double)out[OUT1_BASE + (size_t)(b * NEVENT + i) * REG_STRIDE + SL_SS];
    __shared__ double sd[256];
    __shared__ float sinv;
    sd[tid] = acc;
    __syncthreads();
    for (int off = 128; off > 0; off >>= 1) {
        if (tid < off) sd[tid] += sd[tid + off];
        __syncthreads();
    }
    if (tid == 0) {
        double stdv = sqrt(sd[0] / (double)(M_PER_BATCH - 1));
        sinv = (float)(1.0 / (stdv + 1e-5));
    }
    __syncthreads();
    float inv = sinv;
    for (int i = tid; i < NEVENT; i += 256)
        out[OUT1_BASE + (size_t)(b * NEVENT + i) * REG_STRIDE + SL_INV] = inv;
}

// ---------------------------------------------------------------------------
// Pass 3: finalize. Read own region's scratch into LDS, sync, re-gather raw
// f32 values (events per-XCD L2-resident via swizzle), normalize + affine,
// overwrite the region. float2 slot for (k=8j+kq, pair c2) = 256*j + tid:
// coalesced (wave writes 512 B contiguous).
// ---------------------------------------------------------------------------
__global__ __launch_bounds__(256) void finalize_kernel(
    const float2* __restrict__ xy,
    const float* __restrict__ ev,
    const float* __restrict__ alpha,          // f32 [64]
    const float* __restrict__ beta,           // f32 [64]
    float* __restrict__ out)
{
    int s = swz_query8192(blockIdx.x);
    int b = s >> 11;
    int tid = threadIdx.x;
    float* reg = out + OUT1_BASE + (size_t)s * REG_STRIDE;

    __shared__ int sidx[NSAMPLE];
    __shared__ float sm[CH], sa[CH], sbet[CH];
    __shared__ float sinv;

    if (tid < NSAMPLE) {
        sidx[tid] = ((const int*)reg)[tid];
        sm[tid] = reg[SL_MEAN + tid];
    } else if (tid < 128) {
        sa[tid - 64] = alpha[tid - 64];
        sbet[tid - 64] = beta[tid - 64];
    } else if (tid == 128) {
        sinv = reg[SL_INV];
    }
    __syncthreads();

    int c2 = tid & 31;
    int kq = tid >> 5;
    float inv = sinv;

    const float* evb = ev + (size_t)b * NPTS * DEV;
    const float2* xyb = xy + b * NPTS;

    float m0 = sm[2 * c2],   m1 = sm[2 * c2 + 1];
    float al0 = sa[2 * c2],  al1 = sa[2 * c2 + 1];
    float be0 = sbet[2 * c2], be1 = sbet[2 * c2 + 1];

    float2* outp = (float2*)reg;
#pragma unroll
    for (int j = 0; j < 8; ++j) {
        int row = sidx[8 * j + kq];
        float2 v;
        if (c2 < 31) v = *(const float2*)(evb + (size_t)row * DEV + 2 * c2);
        else         v = xyb[row];
        float2 r;
        r.x = al0 * ((v.x - m0) * inv) + be0;
        r.y = al1 * ((v.y - m1) * inv) + be1;
        outp[256 * j + tid] = r;
    }
}

extern "C" void kernel_launch(void* const* d_in, const int* in_sizes, int n_in,
                              void* d_out, int out_size, void* d_ws, size_t ws_size,
                              hipStream_t stream) {
    const float2* xy    = (const float2*)d_in[0];
    const float*  ev    = (const float*)d_in[1];
    const int*    fps   = (const int*)d_in[2];
    const float*  alpha = (const float*)d_in[3];
    const float*  beta  = (const float*)d_in[4];
    float* out = (float*)d_out;
    (void)d_ws; (void)ws_size;   // intentionally unused

    knn_stats_kernel<<<STOT / 4, 256, 0, stream>>>(xy, ev, fps, out);
    reduce_std_kernel<<<NBATCH, 256, 0, stream>>>(out);
    finalize_kernel<<<STOT, 256, 0, stream>>>(xy, ev, alpha, beta, out);
}